// Round 9
// baseline (8684.893 us; speedup 1.0000x reference)
//
#include <hip/hip_runtime.h>

// ---------------- problem constants ----------------
#define T_SEQ 512
#define P_PRED 32
#define TP 544            // T_SEQ + P_PRED
#define BATCH 256
#define H 512
#define G4H 2048
// ---------------- kernel config --------------------
// 256 WGs = 8 row-groups x 32 col-slots. group = blockIdx&7 (XCD-colocated
// under round-robin dispatch: perf bonus only). Group g owns batch rows
// [32g,32g+32). Slot s owns h-cols [16s,16s+16); wave w owns h-cols
// 16s+4w..+4 (16 gate-cols). Weights in VGPRs (192/lane). A-fragments load
// directly LIC->VGPR (no LDS anywhere). All cross-WG data via sc0|sc1 at the
// LIC coherence point (placement-safe); barriers = device-scope atomics on 8
// group-private lines, fence-free (round-5-validated protocol).
// 1 block/CU, no LDS -> all 256 blocks co-resident (no deadlock).
#define GRID 256
#define BLOCK 256
#define HBUF (BATCH*H)      // elements per h double-buffer slot
#define HBYTES (HBUF*2)
#define SC01 17             // CPol: SC0|SC1 -> bypass L1+L2, operate at LIC

typedef _Float16 half8 __attribute__((ext_vector_type(8)));
typedef float floatx4 __attribute__((ext_vector_type(4)));
typedef __amdgpu_buffer_rsrc_t rsrc_t;

#define MFMA(a,b,c) __builtin_amdgcn_mfma_f32_16x16x32_f16((a),(b),(c),0,0,0)

// ---------------- device-global state --------------
__device__ __attribute__((aligned(128))) _Float16 g_h1[2*HBUF];
__device__ __attribute__((aligned(128))) _Float16 g_h2[2*HBUF];
__device__ __attribute__((aligned(128))) float g_opart[(size_t)TP*BATCH*128]; // [t][row][slot*4+w]
__device__ __attribute__((aligned(128))) float g_seqT[T_SEQ*BATCH];           // [t][row]
__device__ __attribute__((aligned(128))) unsigned g_bar[8*64];                // per-group, 256B apart

__device__ __forceinline__ rsrc_t mkrsrc(void* p){
  return __builtin_amdgcn_make_buffer_rsrc(p, (short)0, -1, 0x00020000);
}
__device__ __forceinline__ half8 ld_h8(rsrc_t r, int off){
  auto v = __builtin_amdgcn_raw_buffer_load_b128(r, off, 0, SC01);
  return __builtin_bit_cast(half8, v);
}
__device__ __forceinline__ floatx4 ld_f4(rsrc_t r, int off){
  auto v = __builtin_amdgcn_raw_buffer_load_b128(r, off, 0, SC01);
  return __builtin_bit_cast(floatx4, v);
}
__device__ __forceinline__ void st_f(rsrc_t r, int off, float v){
  __builtin_amdgcn_raw_buffer_store_b32(__builtin_bit_cast(unsigned, v), r, off, 0, SC01);
}

__device__ __forceinline__ float sigm(float x){ return 1.0f/(1.0f + __expf(-x)); }
__device__ __forceinline__ float tanh_f(float x){ return 1.0f - 2.0f/(1.0f + __expf(2.0f*x)); }

// Group barrier (32 WGs). Release: vmcnt drain (sc stores acked at LIC) +
// __syncthreads. Fence-free: all in-loop data ops are SC01 (coherence point),
// so there is nothing stale in L1/L2 to invalidate. Spin guard converts any
// stall into a fast failing run instead of a hang.
__device__ __forceinline__ void xbar(unsigned* cnt, unsigned target, bool& alive, int tid){
  __builtin_amdgcn_s_waitcnt(0);
  __syncthreads();
  if (tid == 0){
    __hip_atomic_fetch_add(cnt, 1u, __ATOMIC_RELAXED, __HIP_MEMORY_SCOPE_AGENT);
    if (alive){
      int guard = 0;
      while (__hip_atomic_load(cnt, __ATOMIC_RELAXED, __HIP_MEMORY_SCOPE_AGENT) < target){
        __builtin_amdgcn_s_sleep(2);
        if (++guard > (1<<22)){ alive = false; break; }
      }
    }
  }
  __syncthreads();
}

// One pipeline phase. A-fragments load directly LIC->VGPR. DOL1: h1 =
// lstm(x, h1prev). XSEL: 0 = x from seqT, 1 = x from o-partial reduce (+bl).
// DOL2: h2 = lstm(h1r, h2prev) + o-partial store (z2 reuses h1r A-frags).
template<bool DOL1, bool DOL2, int XSEL>
__device__ __forceinline__ void do_phase(
    rsrc_t rh1, rsrc_t rh2, rsrc_t rop, rsrc_t rsq,
    int o_h1r, int o_h2r, int o_h1w, int o_h2w,
    int o_x, float xadd, int t_out,
    const half8 (&wf1)[16], const half8 (&wfx)[16], const half8 (&wfh)[16],
    float b1, float b2, float wx, float wl,
    float (&c1v)[2][4], float (&c2v)[2][4],
    int rowbase, int ln, int quad, int hcb, int sw4)
{
  float xv[2][4];
  if (DOL1){
    #pragma unroll
    for (int mt=0; mt<2; ++mt){
      if (XSEL == 0){
        floatx4 x4 = ld_f4(rsq, o_x + (rowbase + mt*16 + quad*4)*4);
        #pragma unroll
        for (int r=0; r<4; ++r) xv[mt][r] = x4[r] + xadd;
      } else {
        #pragma unroll
        for (int r=0; r<4; ++r){
          const int row = rowbase + mt*16 + quad*4 + r;
          floatx4 v0 = ld_f4(rop, o_x + (row*128 + ln*8)*4);
          floatx4 v1 = ld_f4(rop, o_x + (row*128 + ln*8)*4 + 16);
          float s = v0[0]+v0[1]+v0[2]+v0[3] + v1[0]+v1[1]+v1[2]+v1[3];
          s += __shfl_xor(s, 1, 64);
          s += __shfl_xor(s, 2, 64);
          s += __shfl_xor(s, 4, 64);
          s += __shfl_xor(s, 8, 64);
          xv[mt][r] = s + xadd;
        }
      }
    }
  }

  floatx4 z1[2], z2[2];
  floatx4 zf4 = {0.f,0.f,0.f,0.f};
  z1[0]=zf4; z1[1]=zf4; z2[0]=zf4; z2[1]=zf4;

  const int a_r0 = o_h1r + (rowbase + ln)*H*2;
  const int a_r1 = o_h1r + (rowbase + 16 + ln)*H*2;
  const int a2_r0 = o_h2r + (rowbase + ln)*H*2;
  const int a2_r1 = o_h2r + (rowbase + 16 + ln)*H*2;

  #pragma unroll
  for (int kk = 0; kk < 16; ++kk){
    const int k0b = (kk*32 + quad*8)*2;
    half8 a10 = ld_h8(rh1, a_r0 + k0b);
    half8 a11 = ld_h8(rh1, a_r1 + k0b);
    if (DOL1){
      z1[0] = MFMA(a10, wf1[kk], z1[0]);
      z1[1] = MFMA(a11, wf1[kk], z1[1]);
    }
    if (DOL2){
      z2[0] = MFMA(a10, wfx[kk], z2[0]);
      z2[1] = MFMA(a11, wfx[kk], z2[1]);
      half8 a20 = ld_h8(rh2, a2_r0 + k0b);
      half8 a21 = ld_h8(rh2, a2_r1 + k0b);
      z2[0] = MFMA(a20, wfh[kk], z2[0]);
      z2[1] = MFMA(a21, wfh[kk], z2[1]);
    }
  }

  const bool l4 = (ln < 4);
  const bool evn = ((ln & 1) == 0);
  if (DOL1){
    #pragma unroll
    for (int mt=0; mt<2; ++mt){
      #pragma unroll
      for (int r=0; r<4; ++r){
        const int row = rowbase + mt*16 + quad*4 + r;
        float z = z1[mt][r] + xv[mt][r]*wx + b1;
        float p4  = __shfl_xor(z, 4, 64);
        float p8  = __shfl_xor(z, 8, 64);
        float p12 = __shfl_xor(z, 12, 64);
        float ig = sigm(z), fg = sigm(p4), og = sigm(p8), gg = tanh_f(p12);
        float c = fg*c1v[mt][r] + ig*gg;
        c1v[mt][r] = c;
        float h = og*tanh_f(c);
        unsigned hu = (unsigned)__builtin_bit_cast(unsigned short, (_Float16)h);
        unsigned pn = (unsigned)__shfl_xor((int)hu, 1, 64);
        if (l4 && evn)
          st_f(rh1, o_h1w + (row*H + hcb + ln)*2,
               __builtin_bit_cast(float, hu | (pn<<16)));
      }
    }
  }
  if (DOL2){
    #pragma unroll
    for (int mt=0; mt<2; ++mt){
      #pragma unroll
      for (int r=0; r<4; ++r){
        const int row = rowbase + mt*16 + quad*4 + r;
        float z = z2[mt][r] + b2;
        float p4  = __shfl_xor(z, 4, 64);
        float p8  = __shfl_xor(z, 8, 64);
        float p12 = __shfl_xor(z, 12, 64);
        float ig = sigm(z), fg = sigm(p4), og = sigm(p8), gg = tanh_f(p12);
        float c = fg*c2v[mt][r] + ig*gg;
        c2v[mt][r] = c;
        float h = og*tanh_f(c);
        unsigned hu = (unsigned)__builtin_bit_cast(unsigned short, (_Float16)h);
        unsigned pn = (unsigned)__shfl_xor((int)hu, 1, 64);
        if (l4 && evn)
          st_f(rh2, o_h2w + (row*H + hcb + ln)*2,
               __builtin_bit_cast(float, hu | (pn<<16)));
        float po = l4 ? h*wl : 0.f;
        po += __shfl_xor(po, 1, 64);
        po += __shfl_xor(po, 2, 64);
        if (ln == 0)
          st_f(rop, ((t_out*BATCH + row)*128 + sw4)*4, po);
      }
    }
  }
}

__global__ void reset_kernel(){
  if (threadIdx.x < 8)
    __hip_atomic_store(&g_bar[threadIdx.x*64], 0u, __ATOMIC_RELAXED,
                       __HIP_MEMORY_SCOPE_AGENT);
}

__global__ __launch_bounds__(BLOCK, 1) void sinernn_kernel(
    const float* __restrict__ seq, const float* __restrict__ Wx1,
    const float* __restrict__ bx1, const float* __restrict__ Wh1,
    const float* __restrict__ bh1, const float* __restrict__ Wx2,
    const float* __restrict__ bx2, const float* __restrict__ Wh2,
    const float* __restrict__ bh2, const float* __restrict__ Wl,
    const float* __restrict__ bl,  float* __restrict__ out)
{
  const int tid  = threadIdx.x;
  const int wg   = blockIdx.x;
  const int grp  = wg & 7;             // row group 0..7 (XCD-colocated if RR)
  const int slot = wg >> 3;            // 0..31 within group
  const int w    = tid >> 6;
  const int lane = tid & 63;
  const int ln   = lane & 15;
  const int quad = lane >> 4;
  const int rowbase = grp*32;
  const int hcb  = slot*16 + w*4;      // this wave's 4 h-cols
  const int sw4  = slot*4 + w;         // o-partial slot (0..127)
  unsigned* cnt  = &g_bar[grp*64];

  rsrc_t rh1 = mkrsrc((void*)&g_h1[0]);
  rsrc_t rh2 = mkrsrc((void*)&g_h2[0]);
  rsrc_t rop = mkrsrc((void*)&g_opart[0]);
  rsrc_t rsq = mkrsrc((void*)&g_seqT[0]);

  // gate-col: gate = ln>>2, h-col = hcb + (ln&3)
  const int gc = (ln>>2)*H + hcb + (ln&3);

  // ---- prologue: seqT transpose (this WG: 16 t-values x group rows) ----
  for (int i = tid; i < 16*32; i += BLOCK){
    int t = slot*16 + (i>>5), j = i & 31;
    st_f(rsq, (t*BATCH + rowbase + j)*4, seq[(rowbase+j)*T_SEQ + t]);
  }
  // zero h(-1) (buffer 1) for group rows; redundant across slots, benign
  for (int i = tid; i < 32*H/2; i += BLOCK){
    int off = HBYTES + rowbase*H*2 + i*4;
    st_f(rh1, off, 0.f);
    st_f(rh2, off, 0.f);
  }

  // ---- stage all three weight slices into VGPRs (192/lane) ----
  half8 wf1[16], wfx[16], wfh[16];
  #pragma unroll
  for (int kk = 0; kk < 16; ++kk){
    #pragma unroll
    for (int j = 0; j < 8; ++j){
      const int k = kk*32 + quad*8 + j;
      wf1[kk][j] = (_Float16)Wh1[k*G4H + gc];
      wfx[kk][j] = (_Float16)Wx2[k*G4H + gc];
      wfh[kk][j] = (_Float16)Wh2[k*G4H + gc];
    }
  }
  const float b1 = bx1[gc] + bh1[gc];
  const float b2 = bx2[gc] + bh2[gc];
  const float wx = Wx1[gc];
  const float wl = (ln < 4) ? Wl[hcb + (ln&3)] : 0.f;
  const float blv = bl[0];

  float c1v[2][4] = {{0.f,0.f,0.f,0.f},{0.f,0.f,0.f,0.f}};
  float c2v[2][4] = {{0.f,0.f,0.f,0.f},{0.f,0.f,0.f,0.f}};

  unsigned bidx = 0;
  bool alive = true;
  xbar(cnt, (++bidx)*32u, alive, tid);   // prologue visible group-wide

  // ---- main pipelined region: phase p computes h1(p) and h2(p-1) ----
  for (int p = 0; p < T_SEQ; ++p){
    const int b_h1r = ((p+1)&1)*HBYTES;
    const int b_h1w = (p&1)*HBYTES;
    if (p == 0)
      do_phase<true,false,0>(rh1,rh2,rop,rsq, b_h1r,0, b_h1w,0,
                             0, 0.f, -1, wf1,wfx,wfh, b1,b2,wx,wl,
                             c1v,c2v, rowbase, ln, quad, hcb, sw4);
    else
      do_phase<true,true,0>(rh1,rh2,rop,rsq, b_h1r,(p&1)*HBYTES,
                            b_h1w,((p+1)&1)*HBYTES,
                            p*BATCH*4, 0.f, p-1, wf1,wfx,wfh,
                            b1,b2,wx,wl, c1v,c2v, rowbase, ln, quad, hcb, sw4);
    xbar(cnt, (++bidx)*32u, alive, tid);
  }

  // ---- drain + autoregressive predict ----
  for (int s = T_SEQ-1; s < TP; ++s){
    do_phase<false,true,0>(rh1,rh2,rop,rsq, (s&1)*HBYTES,((s+1)&1)*HBYTES,
                           0,(s&1)*HBYTES,
                           0, 0.f, s, wf1,wfx,wfh, b1,b2,wx,wl,
                           c1v,c2v, rowbase, ln, quad, hcb, sw4);
    xbar(cnt, (++bidx)*32u, alive, tid);
    if (s + 1 < TP){
      do_phase<true,false,1>(rh1,rh2,rop,rsq, (s&1)*HBYTES,0,
                             ((s+1)&1)*HBYTES,0,
                             s*BATCH*128*4, blv, -1, wf1,wfx,wfh,
                             b1,b2,wx,wl, c1v,c2v, rowbase, ln, quad, hcb, sw4);
      xbar(cnt, (++bidx)*32u, alive, tid);
    }
  }

  // ---- epilogue: out[row][t] = sum_{128} opart[t][row][*] + bl ----
  for (int i = 0; i < 17; ++i){
    const int t = slot + i*32;
    const int rj = tid >> 3;
    const int q8 = tid & 7;
    const int row = rowbase + rj;
    const int base = ((t*BATCH + row)*128 + q8*16)*4;
    float s = 0.f;
    #pragma unroll
    for (int k = 0; k < 4; ++k){
      floatx4 v = ld_f4(rop, base + k*16);
      s += v[0]+v[1]+v[2]+v[3];
    }
    s += __shfl_xor(s, 1, 64);
    s += __shfl_xor(s, 2, 64);
    s += __shfl_xor(s, 4, 64);
    if (q8 == 0) out[row*TP + t] = s + blv;
  }
}

extern "C" void kernel_launch(void* const* d_in, const int* in_sizes, int n_in,
                              void* d_out, int out_size, void* d_ws, size_t ws_size,
                              hipStream_t stream) {
  const float* seq = (const float*)d_in[0];
  // d_in[1] = predict (=32, hardcoded)
  const float* Wx1 = (const float*)d_in[2];
  const float* bx1 = (const float*)d_in[3];
  const float* Wh1 = (const float*)d_in[4];
  const float* bh1 = (const float*)d_in[5];
  const float* Wx2 = (const float*)d_in[6];
  const float* bx2 = (const float*)d_in[7];
  const float* Wh2 = (const float*)d_in[8];
  const float* bh2 = (const float*)d_in[9];
  const float* Wl  = (const float*)d_in[10];
  const float* bl  = (const float*)d_in[11];
  float* out = (float*)d_out;

  reset_kernel<<<1, 64, 0, stream>>>();

  sinernn_kernel<<<dim3(GRID), dim3(BLOCK), 0, stream>>>(
      seq, Wx1, bx1, Wh1, bh1, Wx2, bx2, Wh2, bh2, Wl, bl, out);
}

// Round 10
// 7224.121 us; speedup vs baseline: 1.2022x; 1.2022x over previous
//
#include <hip/hip_runtime.h>

// ---------------- problem constants ----------------
#define T_SEQ 512
#define P_PRED 32
#define TP 544            // T_SEQ + P_PRED
#define BATCH 256
#define H 512
#define G4H 2048
// ---------------- kernel config --------------------
// 256 WGs = 8 row-groups x 32 col-slots. group = blockIdx&7. Group g owns
// batch rows [32g,32g+32). Slot s owns h-cols [16s,16s+16); wave w owns
// h-cols 16s+4w..+4 (16 gate-cols). Weights in VGPRs (192/lane). Per phase
// each WG stages its group's h slices LIC->LDS once (round-8 proven), MFMAs
// from LDS. Cross-WG data via sc0|sc1 at LIC (placement-safe). Barrier =
// sense flags: 1 store + 1 wave-wide flag-line load per poll (no RMW).
#define GRID 256
#define BLOCK 256
#define HBUF (BATCH*H)      // elements per h double-buffer slot
#define HBYTES (HBUF*2)
#define SC01 17             // CPol: SC0|SC1 -> bypass L1+L2, operate at LIC

typedef _Float16 half8 __attribute__((ext_vector_type(8)));
typedef float floatx4 __attribute__((ext_vector_type(4)));
typedef __amdgpu_buffer_rsrc_t rsrc_t;

#define MFMA(a,b,c) __builtin_amdgcn_mfma_f32_16x16x32_f16((a),(b),(c),0,0,0)

// ---------------- device-global state --------------
__device__ __attribute__((aligned(128))) _Float16 g_h1[2*HBUF];
__device__ __attribute__((aligned(128))) _Float16 g_h2[2*HBUF];
// o partials: [j = wg*4 + wave][t][32 group-local rows] -> full-line writes
__device__ __attribute__((aligned(128))) float g_opart[(size_t)1024*TP*32];
__device__ __attribute__((aligned(128))) float g_seqT[T_SEQ*BATCH];  // [t][row]
__device__ __attribute__((aligned(128))) unsigned g_flags[8*32];     // 1 line/group

__device__ __forceinline__ rsrc_t mkrsrc(void* p){
  return __builtin_amdgcn_make_buffer_rsrc(p, (short)0, -1, 0x00020000);
}
__device__ __forceinline__ half8 ld_h8(rsrc_t r, int off){
  auto v = __builtin_amdgcn_raw_buffer_load_b128(r, off, 0, SC01);
  return __builtin_bit_cast(half8, v);
}
__device__ __forceinline__ floatx4 ld_f4(rsrc_t r, int off){
  auto v = __builtin_amdgcn_raw_buffer_load_b128(r, off, 0, SC01);
  return __builtin_bit_cast(floatx4, v);
}
__device__ __forceinline__ float ld_f(rsrc_t r, int off){
  auto v = __builtin_amdgcn_raw_buffer_load_b32(r, off, 0, SC01);
  return __builtin_bit_cast(float, v);
}
__device__ __forceinline__ void st_f(rsrc_t r, int off, float v){
  __builtin_amdgcn_raw_buffer_store_b32(__builtin_bit_cast(unsigned, v), r, off, 0, SC01);
}
__device__ __forceinline__ void st_f4(rsrc_t r, int off, floatx4 v){
  __builtin_amdgcn_raw_buffer_store_b128(v, r, off, 0, SC01);
}

__device__ __forceinline__ float sigm(float x){ return 1.0f/(1.0f + __expf(-x)); }
__device__ __forceinline__ float tanh_f(float x){ return 1.0f - 2.0f/(1.0f + __expf(2.0f*x)); }

// Sense-flag group barrier. Release: vmcnt drain (sc stores acked at LIC) +
// __syncthreads; then each WG plain-stores the phase number to its own flag
// slot (no RMW, 32 slots share one 128B line). Wave 0 polls: one load covers
// the whole line (lane&31 -> flag), ballot checks all >= target. Monotone
// phase numbers -> no reset/sense flip needed. Spin guard prevents hangs.
__device__ __forceinline__ void xbar(int grp, int slot, unsigned target,
                                     bool& alive, int tid){
  __builtin_amdgcn_s_waitcnt(0);
  __syncthreads();
  if (tid < 64){
    if (tid == 0)
      __hip_atomic_store(&g_flags[grp*32 + slot], target, __ATOMIC_RELAXED,
                         __HIP_MEMORY_SCOPE_AGENT);
    if (alive){
      int guard = 0;
      for (;;){
        unsigned f = __hip_atomic_load(&g_flags[grp*32 + (tid & 31)],
                                       __ATOMIC_RELAXED, __HIP_MEMORY_SCOPE_AGENT);
        if (__ballot(f >= target) == 0xFFFFFFFFFFFFFFFFull) break;
        __builtin_amdgcn_s_sleep(1);
        if (++guard > (1<<22)){ alive = false; break; }
      }
    }
  }
  __syncthreads();
}

// One pipeline phase. Stages group h slices LIC->LDS (swizzled), MFMAs from
// LDS vs VGPR weights. DOL1: h1 = lstm(x, h1prev); XSEL 0 = x from seqT,
// 1 = x from o-partial gather (+bl). DOL2: h2 = lstm(h1r, h2prev) +
// full-line o-partial store (z2 reuses the staged h1r fragments).
template<bool DOL1, bool DOL2, int XSEL>
__device__ __forceinline__ void do_phase(
    rsrc_t rh1, rsrc_t rh2, rsrc_t rop, rsrc_t rsq,
    int o_h1r, int o_h2r, int o_h1w, int o_h2w,
    int o_x, int xs_t, float xadd, int t_out,
    _Float16* __restrict__ lA1, _Float16* __restrict__ lA2,
    const half8 (&wf1)[16], const half8 (&wfx)[16], const half8 (&wfh)[16],
    float b1, float b2, float wx, float wl,
    float (&c1v)[2][4], float (&c2v)[2][4],
    int rowbase, int grp, int wg4w, int tid, int ln, int quad, int hcb)
{
  // ---- stage A slices (32 rows x 512 fp16) from LIC into swizzled LDS ----
  {
    const int row = tid >> 3, c8 = tid & 7;
    const int gb1 = o_h1r + (rowbase + row)*H*2;
    const int gb2 = o_h2r + (rowbase + row)*H*2;
    #pragma unroll
    for (int g8 = 0; g8 < 8; ++g8){
      const int gran = c8*8 + g8;
      const int loff = row*512 + ((gran ^ (row&7)) << 3);
      half8 v = ld_h8(rh1, gb1 + gran*16);
      *(half8*)(lA1 + loff) = v;
      if (DOL2){
        half8 u = ld_h8(rh2, gb2 + gran*16);
        *(half8*)(lA2 + loff) = u;
      }
    }
  }

  float xv[2][4];
  if (DOL1){
    #pragma unroll
    for (int mt=0; mt<2; ++mt){
      if (XSEL == 0){
        floatx4 x4 = ld_f4(rsq, o_x + (rowbase + mt*16 + quad*4)*4);
        #pragma unroll
        for (int r=0; r<4; ++r) xv[mt][r] = x4[r] + xadd;
      } else {
        #pragma unroll
        for (int r=0; r<4; ++r){
          const int lr = mt*16 + quad*4 + r;   // group-local row
          float s = 0.f;
          #pragma unroll
          for (int cc=0; cc<8; ++cc){
            const int jj = ln*8 + cc;          // 0..127 over (slot',w')
            const int j  = ((jj>>2)*8 + grp)*4 + (jj&3);
            s += ld_f(rop, ((j*TP + xs_t)*32 + lr)*4);
          }
          s += __shfl_xor(s, 1, 64);
          s += __shfl_xor(s, 2, 64);
          s += __shfl_xor(s, 4, 64);
          s += __shfl_xor(s, 8, 64);
          xv[mt][r] = s + xadd;
        }
      }
    }
  }
  __syncthreads();   // staging visible WG-wide

  floatx4 z1[2], z2[2];
  floatx4 zf4 = {0.f,0.f,0.f,0.f};
  z1[0]=zf4; z1[1]=zf4; z2[0]=zf4; z2[1]=zf4;

  #pragma unroll
  for (int kk = 0; kk < 16; ++kk){
    const int sw = (((kk*4 + quad) ^ (ln&7)) << 3);
    half8 a10 = *(const half8*)(lA1 + ln*512 + sw);
    half8 a11 = *(const half8*)(lA1 + (16+ln)*512 + sw);
    if (DOL1){
      z1[0] = MFMA(a10, wf1[kk], z1[0]);
      z1[1] = MFMA(a11, wf1[kk], z1[1]);
    }
    if (DOL2){
      z2[0] = MFMA(a10, wfx[kk], z2[0]);
      z2[1] = MFMA(a11, wfx[kk], z2[1]);
      half8 a20 = *(const half8*)(lA2 + ln*512 + sw);
      half8 a21 = *(const half8*)(lA2 + (16+ln)*512 + sw);
      z2[0] = MFMA(a20, wfh[kk], z2[0]);
      z2[1] = MFMA(a21, wfh[kk], z2[1]);
    }
  }

  const bool l4 = (ln < 4);
  const bool evn = ((ln & 1) == 0);
  if (DOL1){
    #pragma unroll
    for (int mt=0; mt<2; ++mt){
      #pragma unroll
      for (int r=0; r<4; ++r){
        const int row = rowbase + mt*16 + quad*4 + r;
        float z = z1[mt][r] + xv[mt][r]*wx + b1;
        float p4  = __shfl_xor(z, 4, 64);
        float p8  = __shfl_xor(z, 8, 64);
        float p12 = __shfl_xor(z, 12, 64);
        float ig = sigm(z), fg = sigm(p4), og = sigm(p8), gg = tanh_f(p12);
        float c = fg*c1v[mt][r] + ig*gg;
        c1v[mt][r] = c;
        float h = og*tanh_f(c);
        unsigned hu = (unsigned)__builtin_bit_cast(unsigned short, (_Float16)h);
        unsigned pn = (unsigned)__shfl_xor((int)hu, 1, 64);
        if (l4 && evn)
          st_f(rh1, o_h1w + (row*H + hcb + ln)*2,
               __builtin_bit_cast(float, hu | (pn<<16)));
      }
    }
  }
  if (DOL2){
    floatx4 po4[2];
    #pragma unroll
    for (int mt=0; mt<2; ++mt){
      #pragma unroll
      for (int r=0; r<4; ++r){
        const int row = rowbase + mt*16 + quad*4 + r;
        float z = z2[mt][r] + b2;
        float p4  = __shfl_xor(z, 4, 64);
        float p8  = __shfl_xor(z, 8, 64);
        float p12 = __shfl_xor(z, 12, 64);
        float ig = sigm(z), fg = sigm(p4), og = sigm(p8), gg = tanh_f(p12);
        float c = fg*c2v[mt][r] + ig*gg;
        c2v[mt][r] = c;
        float h = og*tanh_f(c);
        unsigned hu = (unsigned)__builtin_bit_cast(unsigned short, (_Float16)h);
        unsigned pn = (unsigned)__shfl_xor((int)hu, 1, 64);
        if (l4 && evn)
          st_f(rh2, o_h2w + (row*H + hcb + ln)*2,
               __builtin_bit_cast(float, hu | (pn<<16)));
        float po = l4 ? h*wl : 0.f;
        po += __shfl_xor(po, 1, 64);
        po += __shfl_xor(po, 2, 64);
        po4[mt][r] = po;              // valid in ln==0 lanes
      }
    }
    if (ln == 0){                     // full 128B line per wave per t
      const int base = ((wg4w*TP + t_out)*32)*4;
      st_f4(rop, base + quad*16, po4[0]);
      st_f4(rop, base + 64 + quad*16, po4[1]);
    }
  }
}

__global__ void reset_kernel(){
  if (threadIdx.x < 8*32)
    __hip_atomic_store(&g_flags[threadIdx.x], 0u, __ATOMIC_RELAXED,
                       __HIP_MEMORY_SCOPE_AGENT);
}

__global__ __launch_bounds__(BLOCK, 1) void sinernn_kernel(
    const float* __restrict__ seq, const float* __restrict__ Wx1,
    const float* __restrict__ bx1, const float* __restrict__ Wh1,
    const float* __restrict__ bh1, const float* __restrict__ Wx2,
    const float* __restrict__ bx2, const float* __restrict__ Wh2,
    const float* __restrict__ bh2, const float* __restrict__ Wl,
    const float* __restrict__ bl,  float* __restrict__ out)
{
  __shared__ __attribute__((aligned(16))) _Float16 lA1[32*512];  // 32 KB
  __shared__ __attribute__((aligned(16))) _Float16 lA2[32*512];  // 32 KB

  const int tid  = threadIdx.x;
  const int wg   = blockIdx.x;
  const int grp  = wg & 7;             // row group 0..7
  const int slot = wg >> 3;            // 0..31 within group
  const int w    = tid >> 6;
  const int lane = tid & 63;
  const int ln   = lane & 15;
  const int quad = lane >> 4;
  const int rowbase = grp*32;
  const int hcb  = slot*16 + w*4;      // this wave's 4 h-cols
  const int wg4w = wg*4 + w;           // o-partial line owner id

  rsrc_t rh1 = mkrsrc((void*)&g_h1[0]);
  rsrc_t rh2 = mkrsrc((void*)&g_h2[0]);
  rsrc_t rop = mkrsrc((void*)&g_opart[0]);
  rsrc_t rsq = mkrsrc((void*)&g_seqT[0]);

  // gate-col: gate = ln>>2, h-col = hcb + (ln&3)
  const int gc = (ln>>2)*H + hcb + (ln&3);

  // ---- prologue: seqT transpose (this WG: 16 t-values x group rows) ----
  for (int i = tid; i < 16*32; i += BLOCK){
    int t = slot*16 + (i>>5), j = i & 31;
    st_f(rsq, (t*BATCH + rowbase + j)*4, seq[(rowbase+j)*T_SEQ + t]);
  }
  // zero h(-1) (buffer 1) for group rows; redundant across slots, benign
  for (int i = tid; i < 32*H/2; i += BLOCK){
    int off = HBYTES + rowbase*H*2 + i*4;
    st_f(rh1, off, 0.f);
    st_f(rh2, off, 0.f);
  }

  // ---- stage all three weight slices into VGPRs (192/lane) ----
  half8 wf1[16], wfx[16], wfh[16];
  #pragma unroll
  for (int kk = 0; kk < 16; ++kk){
    #pragma unroll
    for (int j = 0; j < 8; ++j){
      const int k = kk*32 + quad*8 + j;
      wf1[kk][j] = (_Float16)Wh1[k*G4H + gc];
      wfx[kk][j] = (_Float16)Wx2[k*G4H + gc];
      wfh[kk][j] = (_Float16)Wh2[k*G4H + gc];
    }
  }
  const float b1 = bx1[gc] + bh1[gc];
  const float b2 = bx2[gc] + bh2[gc];
  const float wx = Wx1[gc];
  const float wl = (ln < 4) ? Wl[hcb + (ln&3)] : 0.f;
  const float blv = bl[0];

  float c1v[2][4] = {{0.f,0.f,0.f,0.f},{0.f,0.f,0.f,0.f}};
  float c2v[2][4] = {{0.f,0.f,0.f,0.f},{0.f,0.f,0.f,0.f}};

  unsigned bidx = 0;
  bool alive = true;
  xbar(grp, slot, ++bidx, alive, tid);   // prologue visible group-wide

  // ---- main pipelined region: phase p computes h1(p) and h2(p-1) ----
  for (int p = 0; p < T_SEQ; ++p){
    const int b_h1r = ((p+1)&1)*HBYTES;
    const int b_h1w = (p&1)*HBYTES;
    if (p == 0)
      do_phase<true,false,0>(rh1,rh2,rop,rsq, b_h1r,0, b_h1w,0,
                             0, 0, 0.f, -1, lA1, lA2, wf1,wfx,wfh,
                             b1,b2,wx,wl, c1v,c2v,
                             rowbase, grp, wg4w, tid, ln, quad, hcb);
    else
      do_phase<true,true,0>(rh1,rh2,rop,rsq, b_h1r,(p&1)*HBYTES,
                            b_h1w,((p+1)&1)*HBYTES,
                            p*BATCH*4, 0, 0.f, p-1, lA1, lA2, wf1,wfx,wfh,
                            b1,b2,wx,wl, c1v,c2v,
                            rowbase, grp, wg4w, tid, ln, quad, hcb);
    xbar(grp, slot, ++bidx, alive, tid);
  }

  // ---- drain + autoregressive predict ----
  for (int s = T_SEQ-1; s < TP; ++s){
    do_phase<false,true,0>(rh1,rh2,rop,rsq, (s&1)*HBYTES,((s+1)&1)*HBYTES,
                           0,(s&1)*HBYTES,
                           0, 0, 0.f, s, lA1, lA2, wf1,wfx,wfh,
                           b1,b2,wx,wl, c1v,c2v,
                           rowbase, grp, wg4w, tid, ln, quad, hcb);
    xbar(grp, slot, ++bidx, alive, tid);
    if (s + 1 < TP){
      do_phase<true,false,1>(rh1,rh2,rop,rsq, (s&1)*HBYTES,0,
                             ((s+1)&1)*HBYTES,0,
                             0, s, blv, -1, lA1, lA2, wf1,wfx,wfh,
                             b1,b2,wx,wl, c1v,c2v,
                             rowbase, grp, wg4w, tid, ln, quad, hcb);
      xbar(grp, slot, ++bidx, alive, tid);
    }
  }

  // ---- epilogue: out[row][t] = sum over this group's 128 (slot',w') ----
  {
    float* lred = (float*)lA1;           // reuse staging LDS
    const int row = tid & 31, part = tid >> 5;
    for (int i = 0; i < 17; ++i){
      const int t = slot + i*32;
      float s = 0.f;
      #pragma unroll
      for (int q = 0; q < 16; ++q){
        const int jj = part*16 + q;      // 0..127
        const int j  = ((jj>>2)*8 + grp)*4 + (jj&3);
        s += ld_f(rop, ((j*TP + t)*32 + row)*4);
      }
      __syncthreads();
      lred[part*32 + row] = s;
      __syncthreads();
      if (tid < 32){
        float o = 0.f;
        #pragma unroll
        for (int p2 = 0; p2 < 8; ++p2) o += lred[p2*32 + tid];
        out[(rowbase + tid)*TP + t] = o + blv;
      }
    }
  }
}

extern "C" void kernel_launch(void* const* d_in, const int* in_sizes, int n_in,
                              void* d_out, int out_size, void* d_ws, size_t ws_size,
                              hipStream_t stream) {
  const float* seq = (const float*)d_in[0];
  // d_in[1] = predict (=32, hardcoded)
  const float* Wx1 = (const float*)d_in[2];
  const float* bx1 = (const float*)d_in[3];
  const float* Wh1 = (const float*)d_in[4];
  const float* bh1 = (const float*)d_in[5];
  const float* Wx2 = (const float*)d_in[6];
  const float* bx2 = (const float*)d_in[7];
  const float* Wh2 = (const float*)d_in[8];
  const float* bh2 = (const float*)d_in[9];
  const float* Wl  = (const float*)d_in[10];
  const float* bl  = (const float*)d_in[11];
  float* out = (float*)d_out;

  reset_kernel<<<1, 256, 0, stream>>>();

  sinernn_kernel<<<dim3(GRID), dim3(BLOCK), 0, stream>>>(
      seq, Wx1, bx1, Wh1, bh1, Wx2, bx2, Wh2, bh2, Wl, bl, out);
}